// Round 6
// baseline (1972.811 us; speedup 1.0000x reference)
//
#include <hip/hip_runtime.h>
#include <cstdint>
#include <cstddef>

// ---------------------------------------------------------------------------
// SpikingCoreFlow: bit-exact replication of the JAX reference on MI355X.
//
// Dims: B=128, D_in=1024, n_cores=64, N=256, A=256, n_out=10, cycles=32,
// pool_width = 17410.
//
// Pool "Pb" (bytes, rows of 128 = B):
//   rows [0, 32768)        : spikes, row = t*1024 + d
//   rows [32768, 49152)    : buffer ping (A), row = 32768 + c*256 + n
//   rows [49152, 65536)    : buffer pong (B)
//   row 65536 / 65537      : zeros / ones columns
// Cycle t reads parity A if t even, writes the other.
//
// Exactness (verified R2-R5, absmax == 0.0):
//  - threefry2x32 with jax_threefry_partitionable=True semantics.
//  - einsum 'cna,bca->cbn' = single ascending-a fused-FMA chain from 0 per
//    (c,b,n); memb += E is one more rounded add. v_pk_fma_f32 = 2 independent
//    IEEE FMAs -> per-element chain unchanged -> bit-exact.
//
// Perf journal:
//  R3/R4 (~20us/core): wave-uniform weights -> s_load serialization (~200cy
//    K$ latency, un-pipelined). Lesson: SMEM won't pipeline.
//  R5 (~26us/core): lane=n per-lane weights but Btile=4 -> every wave streams
//    256KB; VMEM RETURN bandwidth (64B/cy/CU into VGPRs) is the wall: 2MB/CU
//    = 13.6us floor. Lesson: weight bytes/FMA must fall via REGISTER reuse.
//  R6: Btile=8 (acc 16 v2f, pk over b-pairs), Nt=256, 1024 single-wave
//    blocks (4 waves/CU, 1/SIMD). Weights: chunk-8 double-buffered coalesced
//    dwordx4 (1KB/wave/a serving 2048 FMA). Masks: bit-packed per wave into
//    256B LDS once, then read as wave-uniform words (readfirstlane -> SALU
//    selects) -- zero per-a LDS/VMEM on the mask path.
//    Budgets: VMEM 6.8us, VALU ~6us, L2 ~7.4us -> ~8us/dispatch.
// ---------------------------------------------------------------------------

#define N_CORES   64
#define NN        256
#define AA        256
#define BB        128
#define DIN       1024
#define NOUT      10
#define CYCLES    32
#define ROW_SPK   0u
#define ROW_A     32768u
#define ROW_B     49152u
#define ROW_ZERO  65536u
#define ROW_ONE   65537u

typedef float v2f __attribute__((ext_vector_type(2)));

__device__ __forceinline__ void tf_round(uint32_t& x0, uint32_t& x1, int r) {
    x0 += x1;
    x1 = (x1 << r) | (x1 >> (32 - r));
    x1 ^= x0;
}

__device__ __forceinline__ void threefry2x32(uint32_t k0, uint32_t k1,
                                             uint32_t c0, uint32_t c1,
                                             uint32_t& o0, uint32_t& o1) {
    uint32_t ks2 = k0 ^ k1 ^ 0x1BD11BDAu;
    uint32_t x0 = c0 + k0, x1 = c1 + k1;
    tf_round(x0,x1,13); tf_round(x0,x1,15); tf_round(x0,x1,26); tf_round(x0,x1,6);
    x0 += k1; x1 += ks2 + 1u;
    tf_round(x0,x1,17); tf_round(x0,x1,29); tf_round(x0,x1,16); tf_round(x0,x1,24);
    x0 += ks2; x1 += k0 + 2u;
    tf_round(x0,x1,13); tf_round(x0,x1,15); tf_round(x0,x1,26); tf_round(x0,x1,6);
    x0 += k0; x1 += k1 + 3u;
    tf_round(x0,x1,17); tf_round(x0,x1,29); tf_round(x0,x1,16); tf_round(x0,x1,24);
    x0 += k1; x1 += ks2 + 4u;
    tf_round(x0,x1,13); tf_round(x0,x1,15); tf_round(x0,x1,26); tf_round(x0,x1,6);
    x0 += ks2; x1 += k0 + 5u;
    o0 = x0; o1 = x1;
}

__global__ void spikes_kernel(const float* __restrict__ x,
                              unsigned char* __restrict__ Pb) {
    __shared__ unsigned char S[32 * 132];
    int bx  = blockIdx.x;        // 1024 = 32 t * 32 dblk
    int t   = bx >> 5;
    int d0  = (bx & 31) * 32;
    int tid = threadIdx.x;

    uint32_t k0, k1;
    threefry2x32(0u, 42u, 0u, (uint32_t)t, k0, k1);   // keys[t] = (w0, w1)

    #pragma unroll
    for (int k = 0; k < 16; ++k) {
        int e  = tid + k * 256;      // 0..4095 = 128 bb * 32 dl
        int bb = e >> 5;
        int dl = e & 31;
        int d  = d0 + dl;
        uint32_t f = (uint32_t)(bb * 1024 + d);
        uint32_t y0, y1;
        threefry2x32(k0, k1, 0u, f, y0, y1);
        uint32_t bits = y0 ^ y1;                      // xor-fold
        float u = __uint_as_float((bits >> 9) | 0x3f800000u) - 1.0f;
        S[dl * 132 + bb] = (u < x[bb * 1024 + d]) ? 1 : 0;
    }
    __syncthreads();

    int dl = tid >> 3;
    int bg = tid & 7;
    const uint32_t* Srow = (const uint32_t*)(S + dl * 132);
    uint4 v;
    v.x = Srow[bg * 4 + 0]; v.y = Srow[bg * 4 + 1];
    v.z = Srow[bg * 4 + 2]; v.w = Srow[bg * 4 + 3];
    size_t row = (size_t)t * 1024 + d0 + dl;
    *(uint4*)(Pb + row * 128 + bg * 16) = v;
}

// WT[c][a][n] = W[c][n][a]
__global__ void wt_kernel(const float* __restrict__ W, float* __restrict__ WT) {
    __shared__ float T[32][33];
    int bx = blockIdx.x;            // 4096 = 64 c * 8 tn * 8 ta
    int c  = bx >> 6;
    int tn = (bx >> 3) & 7;
    int ta = bx & 7;
    int tid = threadIdx.x;
    int r  = tid >> 3;
    int q4 = (tid & 7) * 4;

    const float* src = W + (size_t)c * 65536 + (size_t)(tn * 32 + r) * 256 + ta * 32 + q4;
    float4 v = *(const float4*)src;
    T[r][q4 + 0] = v.x; T[r][q4 + 1] = v.y; T[r][q4 + 2] = v.z; T[r][q4 + 3] = v.w;
    __syncthreads();

    float4 o;
    o.x = T[q4 + 0][r]; o.y = T[q4 + 1][r]; o.z = T[q4 + 2][r]; o.w = T[q4 + 3][r];
    float* dst = WT + (size_t)c * 65536 + (size_t)(ta * 32 + r) * 256 + tn * 32 + q4;
    *(float4*)dst = o;
}

__global__ void offtab_kernel(const int* __restrict__ axon,
                              const int* __restrict__ outsrc,
                              uint32_t* __restrict__ off_tab,
                              uint32_t* __restrict__ out_off) {
    int bx = blockIdx.x;
    int tid = threadIdx.x;
    if (bx < 2048) {
        int idx = bx * 256 + tid;          // [t][c*256+a]
        int t   = idx >> 14;
        int ca  = idx & 16383;
        int j   = axon[ca];
        uint32_t row;
        if (j < 1024)        row = (uint32_t)(t * 1024 + j);
        else if (j < 17408)  row = (((t & 1) == 0) ? ROW_A : ROW_B) + (uint32_t)(j - 1024);
        else                 row = (j == 17408) ? ROW_ZERO : ROW_ONE;
        off_tab[idx] = row * 128u;
    } else {
        for (int idx = tid; idx < CYCLES * NOUT; idx += 256) {
            int t = idx / NOUT, o = idx % NOUT;
            int j = outsrc[o];
            uint32_t row;
            if (j < 1024)        row = (uint32_t)(t * 1024 + j);
            else if (j < 17408)  row = (((t & 1) == 0) ? ROW_B : ROW_A) + (uint32_t)(j - 1024);
            else                 row = (j == 17408) ? ROW_ZERO : ROW_ONE;
            out_off[idx] = row * 128u;
        }
    }
}

// One cycle. 1024 single-wave blocks (64 thr) = (c, bg of 8 b) XCD-swizzled.
// Wave: Bt=8 b, Nt=256 n (lane owns n = 4*lane+nj). Per a: 1 coalesced
// dwordx4 weight load (chunk-8 dbuf), 8 mask bits from wave-uniform SGPR
// word, 16 v_pk_fma_f32 (pk over b-pairs; ascending-a chain -> bit-exact).
__global__ __launch_bounds__(64, 1) void core_kernel(
    const unsigned char* __restrict__ Pb,
    unsigned char* __restrict__ Pw,
    const float* __restrict__ WT,
    const uint32_t* __restrict__ off_t,
    float* __restrict__ memb,
    const float* __restrict__ thresholds,
    uint32_t wbyte_base,
    const uint32_t* __restrict__ out_off_prev,
    float* __restrict__ d_out,
    int do_out)
{
    __shared__ uint32_t lds_mw[64];     // 256 a x 8 mask bits, 4 a per word

    int tid = threadIdx.x;              // == lane (single-wave block)
    int bx  = blockIdx.x;

    // fused out-update for the PREVIOUS cycle (reads buf written last kernel)
    if (do_out && bx < 2) {
        int b = bx * 64 + tid;
        #pragma unroll
        for (int o = 0; o < NOUT; ++o) {
            uint32_t off = out_off_prev[o];
            d_out[b * NOUT + o] += (float)Pb[off + (uint32_t)b];
        }
    }

    // decode: 1024 = 8 xcd * 8 c-local * 16 bg  (c grouped per XCD: 2MB WT/L2)
    int c  = (bx & 7) * 8 + ((bx >> 3) & 7);
    int bg = bx >> 6;                  // 0..15
    int b0 = bg * 8;

    // ---- Phase 1: gather this wave's 8b x 256a masks -> 256B bit-packed LDS
    {
        unsigned char* mbytes = (unsigned char*)lds_mw;
        #pragma unroll
        for (int j = 0; j < 4; ++j) {
            int a = tid + 64 * j;
            uint32_t off = off_t[c * 256 + a];
            const unsigned char* src = Pb + off + (uint32_t)b0;
            uint2 mv = *(const uint2*)src;
            const unsigned char* pb = (const unsigned char*)&mv;
            uint32_t bits = 0;
            #pragma unroll
            for (int k = 0; k < 8; ++k) bits |= (uint32_t)(pb[k] & 1u) << k;
            mbytes[a] = (unsigned char)bits;
        }
    }
    __syncthreads();

    const float* wt = WT + (size_t)c * 65536 + tid * 4;   // + a*256 per iter

    v2f acc[4][4];                     // [nj][bp]: n = 4*tid+nj, b = b0+2*bp(+1)
    #pragma unroll
    for (int nj = 0; nj < 4; ++nj)
        #pragma unroll
        for (int bp = 0; bp < 4; ++bp) acc[nj][bp] = (v2f){0.0f, 0.0f};

    float4 wA[8], wB[8];

#define LOADCH(Wb, ch)                                                        \
    { int a0 = (ch) * 8;                                                      \
      _Pragma("unroll")                                                       \
      for (int i = 0; i < 8; ++i)                                             \
          Wb[i] = *(const float4*)(wt + (size_t)(a0 + i) * 256);              \
    }

#define FMACH(Wb, ch)                                                         \
    { uint32_t mw0 = __builtin_amdgcn_readfirstlane(lds_mw[(ch) * 2]);        \
      uint32_t mw1 = __builtin_amdgcn_readfirstlane(lds_mw[(ch) * 2 + 1]);    \
      _Pragma("unroll")                                                       \
      for (int i = 0; i < 8; ++i) {                                           \
          uint32_t bits = ((i < 4 ? mw0 : mw1) >> (8 * (i & 3))) & 0xFFu;     \
          float4 w = Wb[i];                                                   \
          v2f w0 = (v2f){w.x, w.x};                                           \
          v2f w1 = (v2f){w.y, w.y};                                           \
          v2f w2 = (v2f){w.z, w.z};                                           \
          v2f w3 = (v2f){w.w, w.w};                                           \
          _Pragma("unroll")                                                   \
          for (int bp = 0; bp < 4; ++bp) {                                    \
              float mf0 = (bits >> (2 * bp))     & 1u ? 1.0f : 0.0f;          \
              float mf1 = (bits >> (2 * bp + 1)) & 1u ? 1.0f : 0.0f;          \
              v2f m2 = (v2f){mf0, mf1};                                       \
              acc[0][bp] = __builtin_elementwise_fma(w0, m2, acc[0][bp]);     \
              acc[1][bp] = __builtin_elementwise_fma(w1, m2, acc[1][bp]);     \
              acc[2][bp] = __builtin_elementwise_fma(w2, m2, acc[2][bp]);     \
              acc[3][bp] = __builtin_elementwise_fma(w3, m2, acc[3][bp]);     \
          }                                                                   \
      } }

    LOADCH(wA, 0);
    #pragma unroll
    for (int ch = 0; ch < 32; ch += 2) {
        if (ch + 1 < 32) LOADCH(wB, ch + 1);
        FMACH(wA, ch);
        if (ch + 2 < 32) LOADCH(wA, ch + 2);
        FMACH(wB, ch + 1);
    }
#undef LOADCH
#undef FMACH

    // ---- Epilogue: memb RMW + fired bytes (8 b per nj-row) ----
    float thr = thresholds[c];
    #pragma unroll
    for (int nj = 0; nj < 4; ++nj) {
        int n = 4 * tid + nj;
        size_t rowb = (size_t)(c * 256 + n) * 128 + b0;
        float vv[8];
        {
            float4 m0 = *(const float4*)(memb + rowb);
            float4 m1 = *(const float4*)(memb + rowb + 4);
            vv[0] = m0.x + acc[nj][0].x;  vv[1] = m0.y + acc[nj][0].y;
            vv[2] = m0.z + acc[nj][1].x;  vv[3] = m0.w + acc[nj][1].y;
            vv[4] = m1.x + acc[nj][2].x;  vv[5] = m1.y + acc[nj][2].y;
            vv[6] = m1.z + acc[nj][3].x;  vv[7] = m1.w + acc[nj][3].y;
        }
        uint32_t flo = 0, fhi = 0;
        float st[8];
        #pragma unroll
        for (int k = 0; k < 8; ++k) {
            bool f = vv[k] > thr;
            st[k] = f ? 0.0f : vv[k];
            if (k < 4) flo |= (f ? 1u : 0u) << (8 * k);
            else       fhi |= (f ? 1u : 0u) << (8 * (k - 4));
        }
        float4 s0 = {st[0], st[1], st[2], st[3]};
        float4 s1 = {st[4], st[5], st[6], st[7]};
        *(float4*)(memb + rowb)     = s0;
        *(float4*)(memb + rowb + 4) = s1;
        uint2 fb = {flo, fhi};
        *(uint2*)(Pw + wbyte_base + rowb) = fb;
    }
}

__global__ void tail_kernel(const unsigned char* __restrict__ Pb,
                            const uint32_t* __restrict__ out_off31,
                            float* __restrict__ d_out) {
    int tid = threadIdx.x;
    if (tid < BB) {
        #pragma unroll
        for (int o = 0; o < NOUT; ++o) {
            uint32_t off = out_off31[o];
            d_out[tid * NOUT + o] += (float)Pb[off + (uint32_t)tid];
        }
    }
}

extern "C" void kernel_launch(void* const* d_in, const int* in_sizes, int n_in,
                              void* d_out_, int out_size, void* d_ws, size_t ws_size,
                              hipStream_t stream) {
    const float* x          = (const float*)d_in[0];
    const float* W          = (const float*)d_in[1];
    const float* thresholds = (const float*)d_in[2];
    const int*   axon       = (const int*)d_in[3];
    const int*   outsrc     = (const int*)d_in[4];
    // d_in[5] = cycles; fixed instance -> 32.

    if (ws_size < (size_t)45 * 1024 * 1024) return;

    unsigned char* ws      = (unsigned char*)d_ws;
    unsigned char* Pb      = ws;                                    // 8.4 MB
    float*         WT      = (float*)(ws + (size_t)(16u << 20));    // 16 MiB
    uint32_t*      off_tab = (uint32_t*)(ws + (size_t)(32u << 20)); // 2 MiB
    uint32_t*      out_off = (uint32_t*)(ws + (size_t)(32u << 20) + 2u * 1024u * 1024u);
    float*         memb    = (float*)(ws + (size_t)(36u << 20));    // 8 MiB
    float*         out     = (float*)d_out_;

    hipMemsetAsync(memb, 0, (size_t)N_CORES * NN * BB * sizeof(float), stream);
    hipMemsetAsync(Pb + (size_t)ROW_A * 128, 0, (size_t)16384 * 128, stream);
    hipMemsetAsync(Pb + (size_t)ROW_ZERO * 128, 0, 128, stream);
    hipMemsetAsync(Pb + (size_t)ROW_ONE * 128, 1, 128, stream);
    hipMemsetAsync(out, 0, (size_t)BB * NOUT * sizeof(float), stream);

    spikes_kernel<<<1024, 256, 0, stream>>>(x, Pb);
    wt_kernel<<<4096, 256, 0, stream>>>(W, WT);
    offtab_kernel<<<2049, 256, 0, stream>>>(axon, outsrc, off_tab, out_off);

    for (int t = 0; t < CYCLES; ++t) {
        uint32_t wrow = ((t & 1) == 0) ? ROW_B : ROW_A;   // write parity
        const uint32_t* oprev = out_off + (t > 0 ? (t - 1) * NOUT : 0);
        core_kernel<<<1024, 64, 0, stream>>>(
            Pb, Pb, WT, off_tab + (size_t)t * 16384, memb, thresholds,
            wrow * 128u, oprev, out, t > 0 ? 1 : 0);
    }
    tail_kernel<<<1, 128, 0, stream>>>(Pb, out_off + 31 * NOUT, out);
}

// Round 8
// 752.058 us; speedup vs baseline: 2.6232x; 2.6232x over previous
//
#include <hip/hip_runtime.h>
#include <cstdint>
#include <cstddef>

// ---------------------------------------------------------------------------
// SpikingCoreFlow: bit-exact replication of the JAX reference on MI355X.
//
// Dims: B=128, D_in=1024, n_cores=64, N=256, A=256, n_out=10, cycles=32,
// pool_width = 17410.
//
// Pool "Pb" (bytes, rows of 128 = B):
//   rows [0, 32768)        : spikes, row = t*1024 + d
//   rows [32768, 49152)    : buffer ping (A), row = 32768 + c*256 + n
//   rows [49152, 65536)    : buffer pong (B)
//   row 65536 / 65537      : zeros / ones columns
// Cycle t reads parity A if t even, writes the other.
//
// Exactness (verified R2-R7 first-pass, absmax == 0.0):
//  - threefry2x32 with jax_threefry_partitionable=True semantics.
//  - einsum 'cna,bca->cbn' = single ascending-a fused-FMA chain from 0 per
//    (c,b,n); memb += E is one more rounded add. v_pk_fma_f32 = 2 independent
//    IEEE FMAs -> per-element chain unchanged -> bit-exact.
//
// Perf journal (per core dispatch; floors: FMA 6.8us, VMEM-return@Bt=8 6.8us):
//  R3/R4 ~20us: wave-uniform weights -> s_load serialization. SMEM won't pipe.
//  R5 ~26us: per-lane weights, Bt=4 -> 2MB/CU VMEM return (13.6us floor).
//  R6 ~82us: 1 wave/SIMD exposed every stall; SALU mask machinery 2x VALU.
//  R7: Bt=8, Nt=128/wave, 512x256 = 2 waves/SIMD; weights per-lane dwordx2,
//    masks via uniform ds_read_b128 from LDS floats; 8 pk_fma/a. First-pass
//    absmax 0.0, but POST-TIMING (graph replay + cold relaunch) diverged.
//    Exhaustive audit found no race/coverage/parity bug. R8 removes the only
//    non-kernel graph nodes: the 5 hipMemsetAsync are replaced by init_kernel
//    (graph = kernels only). If post-timing still diverges -> restructure
//    out-update to owner-writes next.
// ---------------------------------------------------------------------------

#define N_CORES   64
#define NN        256
#define AA        256
#define BB        128
#define DIN       1024
#define NOUT      10
#define CYCLES    32
#define ROW_SPK   0u
#define ROW_A     32768u
#define ROW_B     49152u
#define ROW_ZERO  65536u
#define ROW_ONE   65537u

typedef float v2f __attribute__((ext_vector_type(2)));

__device__ __forceinline__ void tf_round(uint32_t& x0, uint32_t& x1, int r) {
    x0 += x1;
    x1 = (x1 << r) | (x1 >> (32 - r));
    x1 ^= x0;
}

__device__ __forceinline__ void threefry2x32(uint32_t k0, uint32_t k1,
                                             uint32_t c0, uint32_t c1,
                                             uint32_t& o0, uint32_t& o1) {
    uint32_t ks2 = k0 ^ k1 ^ 0x1BD11BDAu;
    uint32_t x0 = c0 + k0, x1 = c1 + k1;
    tf_round(x0,x1,13); tf_round(x0,x1,15); tf_round(x0,x1,26); tf_round(x0,x1,6);
    x0 += k1; x1 += ks2 + 1u;
    tf_round(x0,x1,17); tf_round(x0,x1,29); tf_round(x0,x1,16); tf_round(x0,x1,24);
    x0 += ks2; x1 += k0 + 2u;
    tf_round(x0,x1,13); tf_round(x0,x1,15); tf_round(x0,x1,26); tf_round(x0,x1,6);
    x0 += k0; x1 += k1 + 3u;
    tf_round(x0,x1,17); tf_round(x0,x1,29); tf_round(x0,x1,16); tf_round(x0,x1,24);
    x0 += k1; x1 += ks2 + 4u;
    tf_round(x0,x1,13); tf_round(x0,x1,15); tf_round(x0,x1,26); tf_round(x0,x1,6);
    x0 += ks2; x1 += k0 + 5u;
    o0 = x0; o1 = x1;
}

// All launch-time state init in ONE kernel (replaces 5 hipMemsetAsync):
// memb (8 MiB) = 0, buffer ping ROW_A (2 MiB) = 0, zeros row = 0,
// ones row = 0x01 bytes, out (1280 floats) = 0.
__global__ void init_kernel(unsigned char* __restrict__ Pb,
                            float* __restrict__ memb,
                            float* __restrict__ out) {
    int idx = blockIdx.x * 256 + threadIdx.x;       // 2048 blocks -> 524288
    float4 z = {0.0f, 0.0f, 0.0f, 0.0f};
    *(float4*)(memb + (size_t)idx * 4) = z;                         // 8 MiB
    *(uint32_t*)(Pb + (size_t)ROW_A * 128 + (size_t)idx * 4) = 0u;  // 2 MiB
    if (idx < 32)
        *(uint32_t*)(Pb + (size_t)ROW_ZERO * 128 + idx * 4) = 0u;
    else if (idx < 64)
        *(uint32_t*)(Pb + (size_t)ROW_ONE * 128 + (idx - 32) * 4) = 0x01010101u;
    if (idx < BB * NOUT)
        out[idx] = 0.0f;
}

__global__ void spikes_kernel(const float* __restrict__ x,
                              unsigned char* __restrict__ Pb) {
    __shared__ unsigned char S[32 * 132];
    int bx  = blockIdx.x;        // 1024 = 32 t * 32 dblk
    int t   = bx >> 5;
    int d0  = (bx & 31) * 32;
    int tid = threadIdx.x;

    uint32_t k0, k1;
    threefry2x32(0u, 42u, 0u, (uint32_t)t, k0, k1);   // keys[t] = (w0, w1)

    #pragma unroll
    for (int k = 0; k < 16; ++k) {
        int e  = tid + k * 256;      // 0..4095 = 128 bb * 32 dl
        int bb = e >> 5;
        int dl = e & 31;
        int d  = d0 + dl;
        uint32_t f = (uint32_t)(bb * 1024 + d);
        uint32_t y0, y1;
        threefry2x32(k0, k1, 0u, f, y0, y1);
        uint32_t bits = y0 ^ y1;                      // xor-fold
        float u = __uint_as_float((bits >> 9) | 0x3f800000u) - 1.0f;
        S[dl * 132 + bb] = (u < x[bb * 1024 + d]) ? 1 : 0;
    }
    __syncthreads();

    int dl = tid >> 3;
    int bg = tid & 7;
    const uint32_t* Srow = (const uint32_t*)(S + dl * 132);
    uint4 v;
    v.x = Srow[bg * 4 + 0]; v.y = Srow[bg * 4 + 1];
    v.z = Srow[bg * 4 + 2]; v.w = Srow[bg * 4 + 3];
    size_t row = (size_t)t * 1024 + d0 + dl;
    *(uint4*)(Pb + row * 128 + bg * 16) = v;
}

// WT[c][a][n] = W[c][n][a]
__global__ void wt_kernel(const float* __restrict__ W, float* __restrict__ WT) {
    __shared__ float T[32][33];
    int bx = blockIdx.x;            // 4096 = 64 c * 8 tn * 8 ta
    int c  = bx >> 6;
    int tn = (bx >> 3) & 7;
    int ta = bx & 7;
    int tid = threadIdx.x;
    int r  = tid >> 3;
    int q4 = (tid & 7) * 4;

    const float* src = W + (size_t)c * 65536 + (size_t)(tn * 32 + r) * 256 + ta * 32 + q4;
    float4 v = *(const float4*)src;
    T[r][q4 + 0] = v.x; T[r][q4 + 1] = v.y; T[r][q4 + 2] = v.z; T[r][q4 + 3] = v.w;
    __syncthreads();

    float4 o;
    o.x = T[q4 + 0][r]; o.y = T[q4 + 1][r]; o.z = T[q4 + 2][r]; o.w = T[q4 + 3][r];
    float* dst = WT + (size_t)c * 65536 + (size_t)(ta * 32 + r) * 256 + tn * 32 + q4;
    *(float4*)dst = o;
}

__global__ void offtab_kernel(const int* __restrict__ axon,
                              const int* __restrict__ outsrc,
                              uint32_t* __restrict__ off_tab,
                              uint32_t* __restrict__ out_off) {
    int bx = blockIdx.x;
    int tid = threadIdx.x;
    if (bx < 2048) {
        int idx = bx * 256 + tid;          // [t][c*256+a]
        int t   = idx >> 14;
        int ca  = idx & 16383;
        int j   = axon[ca];
        uint32_t row;
        if (j < 1024)        row = (uint32_t)(t * 1024 + j);
        else if (j < 17408)  row = (((t & 1) == 0) ? ROW_A : ROW_B) + (uint32_t)(j - 1024);
        else                 row = (j == 17408) ? ROW_ZERO : ROW_ONE;
        off_tab[idx] = row * 128u;
    } else {
        for (int idx = tid; idx < CYCLES * NOUT; idx += 256) {
            int t = idx / NOUT, o = idx % NOUT;
            int j = outsrc[o];
            uint32_t row;
            if (j < 1024)        row = (uint32_t)(t * 1024 + j);
            else if (j < 17408)  row = (((t & 1) == 0) ? ROW_B : ROW_A) + (uint32_t)(j - 1024);
            else                 row = (j == 17408) ? ROW_ZERO : ROW_ONE;
            out_off[idx] = row * 128u;
        }
    }
}

// One cycle. 512 blocks x 256 thr (4 waves) = (c, bg of 16 b), XCD-swizzled.
// Wave w: b-oct = bg*16 + (w&1)*8, n-half = (w>>1)*128; lane owns n-pair.
// Phase 1: expand 256a x 16b masks -> LDS floats (rows padded to 20 floats).
// Loop per a: 1 global dwordx2 (weights, per-lane coalesced) + 2 uniform
// ds_read_b128 (8 mask floats, broadcast) + 8 v_pk_fma_f32 (ascending-a
// chain per (n,b) -> bit-exact). Zero VALU on the mask path.
#define MF_ST 20   // Mf row stride in floats (80B: 16B-aligned, banks spread)

__global__ __launch_bounds__(256, 2) void core_kernel(
    const unsigned char* __restrict__ Pb,
    unsigned char* __restrict__ Pw,
    const float* __restrict__ WT,
    const uint32_t* __restrict__ off_t,
    float* __restrict__ memb,
    const float* __restrict__ thresholds,
    uint32_t wbyte_base,
    const uint32_t* __restrict__ out_off_prev,
    float* __restrict__ d_out,
    int do_out)
{
    __shared__ float Mf[256 * MF_ST];   // 20 KB

    int tid = threadIdx.x;
    int bx  = blockIdx.x;

    // fused out-update for the PREVIOUS cycle (reads buf written last kernel;
    // that region is the current READ parity -> never written by this kernel)
    if (do_out && bx == 0 && tid < BB) {
        #pragma unroll
        for (int o = 0; o < NOUT; ++o) {
            uint32_t off = out_off_prev[o];
            d_out[tid * NOUT + o] += (float)Pb[off + (uint32_t)tid];
        }
    }

    // decode: 512 = 8 xcd * 8 c-local * 8 bg  (c grouped per XCD: 2MB WT/L2)
    int c     = (bx & 7) * 8 + ((bx >> 3) & 7);
    int bg    = bx >> 6;               // 0..7
    int b0blk = bg * 16;

    // ---- Phase 1: expand masks -> LDS floats (thread = a) ----
    {
        uint32_t off = off_t[c * 256 + tid];            // coalesced
        uint4 v = *(const uint4*)(Pb + off + (uint32_t)b0blk);
        const unsigned char* pb = (const unsigned char*)&v;
        float* dst = Mf + tid * MF_ST;
        #pragma unroll
        for (int q = 0; q < 4; ++q) {
            float4 f;
            f.x = (float)pb[4 * q + 0];
            f.y = (float)pb[4 * q + 1];
            f.z = (float)pb[4 * q + 2];
            f.w = (float)pb[4 * q + 3];
            *(float4*)(dst + 4 * q) = f;
        }
    }
    __syncthreads();

    int lane = tid & 63;
    int wid  = __builtin_amdgcn_readfirstlane(tid >> 6);
    int bo   = wid & 1;                // b-oct within the 16
    int nh   = wid >> 1;               // n-half
    int b0   = b0blk + bo * 8;
    int n0   = nh * 128;

    const float* wt   = WT + (size_t)c * 65536 + n0 + lane * 2;  // +a*256/iter
    const float* mrow = Mf + bo * 8;                             // +a*MF_ST/iter

    v2f acc0[4], acc1[4];              // nj=0/1, bp=0..3 (b pairs)
    #pragma unroll
    for (int bp = 0; bp < 4; ++bp) { acc0[bp] = (v2f){0.f, 0.f}; acc1[bp] = (v2f){0.f, 0.f}; }

    // ---- Hot loop: exact ascending-a chain ----
    #pragma unroll 4
    for (int a = 0; a < 256; ++a) {
        v2f w = *(const v2f*)(wt + (size_t)a * 256);        // per-lane dwordx2
        float4 mlo = *(const float4*)(mrow + a * MF_ST);    // uniform b128
        float4 mhi = *(const float4*)(mrow + a * MF_ST + 4);
        v2f m0 = {mlo.x, mlo.y};
        v2f m1 = {mlo.z, mlo.w};
        v2f m2 = {mhi.x, mhi.y};
        v2f m3 = {mhi.z, mhi.w};
        v2f w0 = {w.x, w.x};
        v2f w1 = {w.y, w.y};
        acc0[0] = __builtin_elementwise_fma(w0, m0, acc0[0]);
        acc0[1] = __builtin_elementwise_fma(w0, m1, acc0[1]);
        acc0[2] = __builtin_elementwise_fma(w0, m2, acc0[2]);
        acc0[3] = __builtin_elementwise_fma(w0, m3, acc0[3]);
        acc1[0] = __builtin_elementwise_fma(w1, m0, acc1[0]);
        acc1[1] = __builtin_elementwise_fma(w1, m1, acc1[1]);
        acc1[2] = __builtin_elementwise_fma(w1, m2, acc1[2]);
        acc1[3] = __builtin_elementwise_fma(w1, m3, acc1[3]);
    }

    // ---- Epilogue: memb RMW + fired bytes (2 n-rows x 8 b per lane) ----
    float thr = thresholds[c];
    #pragma unroll
    for (int nj = 0; nj < 2; ++nj) {
        int n = n0 + 2 * lane + nj;
        size_t rowb = (size_t)(c * 256 + n) * 128 + b0;
        const v2f* accp = (nj == 0) ? acc0 : acc1;
        float4 m0 = *(const float4*)(memb + rowb);
        float4 m1 = *(const float4*)(memb + rowb + 4);
        float vv[8];
        vv[0] = m0.x + accp[0].x;  vv[1] = m0.y + accp[0].y;
        vv[2] = m0.z + accp[1].x;  vv[3] = m0.w + accp[1].y;
        vv[4] = m1.x + accp[2].x;  vv[5] = m1.y + accp[2].y;
        vv[6] = m1.z + accp[3].x;  vv[7] = m1.w + accp[3].y;
        uint32_t flo = 0, fhi = 0;
        float st[8];
        #pragma unroll
        for (int k = 0; k < 8; ++k) {
            bool f = vv[k] > thr;
            st[k] = f ? 0.0f : vv[k];
            if (k < 4) flo |= (f ? 1u : 0u) << (8 * k);
            else       fhi |= (f ? 1u : 0u) << (8 * (k - 4));
        }
        float4 s0 = {st[0], st[1], st[2], st[3]};
        float4 s1 = {st[4], st[5], st[6], st[7]};
        *(float4*)(memb + rowb)     = s0;
        *(float4*)(memb + rowb + 4) = s1;
        uint2 fb = {flo, fhi};
        *(uint2*)(Pw + wbyte_base + rowb) = fb;
    }
}

__global__ void tail_kernel(const unsigned char* __restrict__ Pb,
                            const uint32_t* __restrict__ out_off31,
                            float* __restrict__ d_out) {
    int tid = threadIdx.x;
    if (tid < BB) {
        #pragma unroll
        for (int o = 0; o < NOUT; ++o) {
            uint32_t off = out_off31[o];
            d_out[tid * NOUT + o] += (float)Pb[off + (uint32_t)tid];
        }
    }
}

extern "C" void kernel_launch(void* const* d_in, const int* in_sizes, int n_in,
                              void* d_out_, int out_size, void* d_ws, size_t ws_size,
                              hipStream_t stream) {
    const float* x          = (const float*)d_in[0];
    const float* W          = (const float*)d_in[1];
    const float* thresholds = (const float*)d_in[2];
    const int*   axon       = (const int*)d_in[3];
    const int*   outsrc     = (const int*)d_in[4];
    // d_in[5] = cycles; fixed instance -> 32.

    if (ws_size < (size_t)45 * 1024 * 1024) return;

    unsigned char* ws      = (unsigned char*)d_ws;
    unsigned char* Pb      = ws;                                    // 8.4 MB
    float*         WT      = (float*)(ws + (size_t)(16u << 20));    // 16 MiB
    uint32_t*      off_tab = (uint32_t*)(ws + (size_t)(32u << 20)); // 2 MiB
    uint32_t*      out_off = (uint32_t*)(ws + (size_t)(32u << 20) + 2u * 1024u * 1024u);
    float*         memb    = (float*)(ws + (size_t)(36u << 20));    // 8 MiB
    float*         out     = (float*)d_out_;

    init_kernel<<<2048, 256, 0, stream>>>(Pb, memb, out);
    spikes_kernel<<<1024, 256, 0, stream>>>(x, Pb);
    wt_kernel<<<4096, 256, 0, stream>>>(W, WT);
    offtab_kernel<<<2049, 256, 0, stream>>>(axon, outsrc, off_tab, out_off);

    for (int t = 0; t < CYCLES; ++t) {
        uint32_t wrow = ((t & 1) == 0) ? ROW_B : ROW_A;   // write parity
        const uint32_t* oprev = out_off + (t > 0 ? (t - 1) * NOUT : 0);
        core_kernel<<<512, 256, 0, stream>>>(
            Pb, Pb, WT, off_tab + (size_t)t * 16384, memb, thresholds,
            wrow * 128u, oprev, out, t > 0 ? 1 : 0);
    }
    tail_kernel<<<1, 128, 0, stream>>>(Pb, out_off + 31 * NOUT, out);
}